// Round 7
// baseline (14795.370 us; speedup 1.0000x reference)
//
#include <hip/hip_runtime.h>

// 2-layer LSTM (H=256, T=256, B=512, I=2) + linear head.
// 256 blocks x 1024 threads (1 block/CU via __launch_bounds__(1024,4)),
// 2 batch elements per block, t-loop in-kernel.
// Weight stream fp16: 96 logical chunks/step (chunk = 8 k x 1024 gate-rows,
// 16 B per thread). 20 chunks PARKED (17 in VGPRs: vp0..vp16; 3 in LDS),
// 76 streamed from L2 through a 4-buffer register pipeline (76 % 4 == 0 so
// the rotation phase is identical every step; explicit 96-slot unrolled
// sequence). usec uses union sub-register views -> fdot2 operands are raw
// VGPRs (no pack/perm VALU). h in LDS fp16 (broadcast b128), c in regs,
// 4 barriers/step.
// Lessons: R3 no cross-block exchange; R5 parked regs only under an
// explicit launch-bounds occupancy contract (spill -> scratch -> L2 thrash).

typedef float vf2 __attribute__((ext_vector_type(2)));
typedef _Float16 vh2 __attribute__((ext_vector_type(2)));
typedef _Float16 vh4 __attribute__((ext_vector_type(4)));
typedef _Float16 vh8 __attribute__((ext_vector_type(8)));

#define NT 1024
#define TSTEPS 256
#define NCH 96            // logical chunks per step
#define NSTRM 76          // streamed chunks per step
#define CHB 16384         // bytes per chunk = 1024 threads * 16 B
#define FS 393216         // fp32 table offset (floats) = 96*CHB/4

// parked set: ch%5==4 (19 chunks) plus ch==91 -> 20 parked, 76 streamed.
// storage order: streamed chunks at positions [0..76) in logical order;
// parked at [76..96) in logical order (76..92 -> VGPR vp0..vp16,
// 93..95 -> LDS slots 0..2).

__global__ void prep_kernel(const float* __restrict__ W_ih1,
                            const float* __restrict__ W_hh1,
                            const float* __restrict__ b_ih1,
                            const float* __restrict__ b_hh1,
                            const float* __restrict__ W_ih2,
                            const float* __restrict__ W_hh2,
                            const float* __restrict__ b_ih2,
                            const float* __restrict__ b_hh2,
                            void* __restrict__ ws) {
    const int stride = gridDim.x * blockDim.x;
    const int idx = blockIdx.x * blockDim.x + threadIdx.x;
    _Float16* wh = (_Float16*)ws;
    float* wf = (float*)ws;
    // logical chunk ch covers k = 8*ch..8*ch+7 for all 1024 gate-rows.
    // k<256: W_hh1 | k<512: W_ih2 | else W_hh2.
    for (int e = idx; e < NCH * 8192; e += stride) {
        int ch = e >> 13, rem = e & 8191, row = rem >> 3, i = rem & 7;
        int k = (ch << 3) + i;
        float v;
        if (k < 256)      v = W_hh1[row * 256 + k];
        else if (k < 512) v = W_ih2[row * 256 + (k - 256)];
        else              v = W_hh2[row * 256 + (k - 512)];
        bool parked = ((ch % 5) == 4) || (ch == 91);
        int adj = (ch > 91) ? 1 : 0;
        int pos = parked ? (NSTRM + ch / 5 + adj)
                         : (ch - ch / 5 - adj);
        wh[pos * 8192 + rem] = (_Float16)v;
    }
    for (int j = idx; j < 1024; j += stride) {
        wf[FS + j]        = W_ih1[j * 2 + 0];
        wf[FS + 1024 + j] = W_ih1[j * 2 + 1];
        wf[FS + 2048 + j] = b_ih1[j] + b_hh1[j];
        wf[FS + 3072 + j] = b_ih2[j] + b_hh2[j];
    }
}

__device__ __forceinline__ float sig_(float v) {
    return 1.f / (1.f + __expf(-v));
}
__device__ __forceinline__ float tanh_(float v) {
    return 1.f - 2.f / (__expf(2.f * v) + 1.f);
}
__device__ __forceinline__ float fdot2_(vh2 a, vh2 b, float c) {
#if __has_builtin(__builtin_amdgcn_fdot2)
    return __builtin_amdgcn_fdot2(a, b, c, false);
#else
    return c + (float)a.x * (float)b.x + (float)a.y * (float)b.y;
#endif
}

union W8 { vh8 v; vh2 p[4]; };

// streamed slot: consume BUF then refill it from the stream
#define US(BUF, HP, KL) { usec(BUF, HP, KL); loadc(BUF); }
// VGPR-parked slot
#define UP(VP, HP, KL)  { usec(VP, HP, KL); }
// LDS-parked slot
#define UL(S, HP, KL)   { vh8 t_ = *(const vh8*)&lds_park[S][t16]; usec(t_, HP, KL); }

__global__ __launch_bounds__(NT, 4) void lstm_kernel(
    const float* __restrict__ x,      // (512, 256, 2)
    const void* __restrict__ ws,
    const float* __restrict__ W_lin,  // (2, 256)
    const float* __restrict__ b_lin,  // (2,)
    float* __restrict__ out)          // (512, 256, 2)
{
    __shared__ float gbuf[2][1024];            // gate preacts [batch][row]
    __shared__ _Float16 hl1[2][2][256];        // h1 [parity][batch][unit]
    __shared__ _Float16 hl2[2][2][256];        // h2
    __shared__ char lds_park[3][CHB];          // 3 LDS-parked chunks (48 KB)

    const int tid = threadIdx.x;
    const int j = tid;                         // owned gate-row
    const int u = tid & 255, bu = (tid >> 8) & 1;
    const int b0 = blockIdx.x * 2;
    const char* wstream = (const char*)ws;
    const float* wf = (const float*)ws;

    const float wx0 = wf[FS + j], wx1 = wf[FS + 1024 + j];
    const float bj1 = wf[FS + 2048 + j], bj2 = wf[FS + 3072 + j];

    // y-head: waves 0..3 -> (batch ob, output oo); lane covers 4 units
    const int lane = tid & 63, wv = tid >> 6;
    const int ob = (wv >> 1) & 1, oo = wv & 1;
    const float wl0 = W_lin[oo * 256 + 4 * lane + 0];
    const float wl1 = W_lin[oo * 256 + 4 * lane + 1];
    const float wl2 = W_lin[oo * 256 + 4 * lane + 2];
    const float wl3 = W_lin[oo * 256 + 4 * lane + 3];
    const float blin = b_lin[oo];

    for (int i = tid; i < 2 * 2 * 256; i += NT) {
        ((_Float16*)hl1)[i] = (_Float16)0.f;
        ((_Float16*)hl2)[i] = (_Float16)0.f;
    }

    float c1 = 0.f, c2 = 0.f;
    vf2 xv0 = *(const vf2*)(x + (size_t)(b0 + 0) * 512);
    vf2 xv1 = *(const vf2*)(x + (size_t)(b0 + 1) * 512);

    const int t16 = tid * 16;
    int sp = 0;                                // uniform stream byte offset
    float acc0, acc1;

    auto loadc = [&](vh8& dst) {
        dst = *(const vh8*)(wstream + sp + t16);
        sp += CHB;
        if (sp == NSTRM * CHB) sp = 0;
    };
    auto usec = [&](vh8 w, const _Float16 (*hp)[256], int k0) {
        W8 uw; uw.v = w;
        W8 ua; ua.v = *(const vh8*)&hp[0][k0];
        W8 ub; ub.v = *(const vh8*)&hp[1][k0];
        acc0 = fdot2_(uw.p[0], ua.p[0], acc0);
        acc0 = fdot2_(uw.p[1], ua.p[1], acc0);
        acc0 = fdot2_(uw.p[2], ua.p[2], acc0);
        acc0 = fdot2_(uw.p[3], ua.p[3], acc0);
        acc1 = fdot2_(uw.p[0], ub.p[0], acc1);
        acc1 = fdot2_(uw.p[1], ub.p[1], acc1);
        acc1 = fdot2_(uw.p[2], ub.p[2], acc1);
        acc1 = fdot2_(uw.p[3], ub.p[3], acc1);
    };

    // park 17 chunks in VGPRs (positions 76..92) and 3 in LDS (93..95)
    #define LDP(P) (*(const vh8*)(wstream + (size_t)(P) * CHB + t16))
    vh8 vp0  = LDP(76), vp1  = LDP(77), vp2  = LDP(78), vp3  = LDP(79);
    vh8 vp4  = LDP(80), vp5  = LDP(81), vp6  = LDP(82), vp7  = LDP(83);
    vh8 vp8  = LDP(84), vp9  = LDP(85), vp10 = LDP(86), vp11 = LDP(87);
    vh8 vp12 = LDP(88), vp13 = LDP(89), vp14 = LDP(90), vp15 = LDP(91);
    vh8 vp16 = LDP(92);
    *(vh8*)&lds_park[0][t16] = LDP(93);
    *(vh8*)&lds_park[1][t16] = LDP(94);
    *(vh8*)&lds_park[2][t16] = LDP(95);
    #undef LDP

    vh8 bA, bB, bC, bD;
    loadc(bA); loadc(bB); loadc(bC); loadc(bD);
    __syncthreads();

    #pragma unroll 1
    for (int t = 0; t < TSTEPS; ++t) {
        const int p = t & 1, pm = p ^ 1;
        const _Float16 (*hpA)[256] = hl1[pm];
        const _Float16 (*hpB)[256] = hl1[p];
        const _Float16 (*hpC)[256] = hl2[pm];

        // ---- layer 1 gates: b1 + Wih1*x_t + Whh1*h1(t-1) [chunks 0..31] ----
        acc0 = bj1 + wx0 * xv0.x + wx1 * xv0.y;
        acc1 = bj1 + wx0 * xv1.x + wx1 * xv1.y;
        US(bA,hpA,0)   US(bB,hpA,8)   US(bC,hpA,16)  US(bD,hpA,24)
        UP(vp0,hpA,32)
        US(bA,hpA,40)  US(bB,hpA,48)  US(bC,hpA,56)  US(bD,hpA,64)
        UP(vp1,hpA,72)
        US(bA,hpA,80)  US(bB,hpA,88)  US(bC,hpA,96)  US(bD,hpA,104)
        UP(vp2,hpA,112)
        US(bA,hpA,120) US(bB,hpA,128) US(bC,hpA,136) US(bD,hpA,144)
        UP(vp3,hpA,152)
        US(bA,hpA,160) US(bB,hpA,168) US(bC,hpA,176) US(bD,hpA,184)
        UP(vp4,hpA,192)
        US(bA,hpA,200) US(bB,hpA,208) US(bC,hpA,216) US(bD,hpA,224)
        UP(vp5,hpA,232)
        US(bA,hpA,240) US(bB,hpA,248)
        gbuf[0][j] = acc0; gbuf[1][j] = acc1;
        __syncthreads();

        // ---- layer 1 cell update (threads 0..511: unit u, batch bu) ----
        if (tid < 512) {
            float gi = sig_(gbuf[bu][u]);
            float gf = sig_(gbuf[bu][256 + u]);
            float gg = tanh_(gbuf[bu][512 + u]);
            float go = sig_(gbuf[bu][768 + u]);
            c1 = gf * c1 + gi * gg;
            hl1[p][bu][u] = (_Float16)(go * tanh_(c1));
        }
        __syncthreads();

        // ---- layer 2 gates: b2 + Wih2*h1(t) [32..63] + Whh2*h2(t-1) [64..95] ----
        acc0 = bj2; acc1 = bj2;
        US(bC,hpB,0)   US(bD,hpB,8)
        UP(vp6,hpB,16)
        US(bA,hpB,24)  US(bB,hpB,32)  US(bC,hpB,40)  US(bD,hpB,48)
        UP(vp7,hpB,56)
        US(bA,hpB,64)  US(bB,hpB,72)  US(bC,hpB,80)  US(bD,hpB,88)
        UP(vp8,hpB,96)
        US(bA,hpB,104) US(bB,hpB,112) US(bC,hpB,120) US(bD,hpB,128)
        UP(vp9,hpB,136)
        US(bA,hpB,144) US(bB,hpB,152) US(bC,hpB,160) US(bD,hpB,168)
        UP(vp10,hpB,176)
        US(bA,hpB,184) US(bB,hpB,192) US(bC,hpB,200) US(bD,hpB,208)
        UP(vp11,hpB,216)
        US(bA,hpB,224) US(bB,hpB,232) US(bC,hpB,240) US(bD,hpB,248)
        UP(vp12,hpC,0)
        US(bA,hpC,8)   US(bB,hpC,16)  US(bC,hpC,24)  US(bD,hpC,32)
        UP(vp13,hpC,40)
        US(bA,hpC,48)  US(bB,hpC,56)  US(bC,hpC,64)  US(bD,hpC,72)
        UP(vp14,hpC,80)
        US(bA,hpC,88)  US(bB,hpC,96)  US(bC,hpC,104) US(bD,hpC,112)
        UP(vp15,hpC,120)
        US(bA,hpC,128) US(bB,hpC,136) US(bC,hpC,144) US(bD,hpC,152)
        UP(vp16,hpC,160)
        US(bA,hpC,168) US(bB,hpC,176) US(bC,hpC,184) US(bD,hpC,192)
        UL(0,hpC,200)
        US(bA,hpC,208)
        UL(1,hpC,216)
        US(bB,hpC,224) US(bC,hpC,232)
        UL(2,hpC,240)
        US(bD,hpC,248)
        gbuf[0][j] = acc0; gbuf[1][j] = acc1;
        __syncthreads();

        // ---- layer 2 cell update ----
        if (tid < 512) {
            float gi = sig_(gbuf[bu][u]);
            float gf = sig_(gbuf[bu][256 + u]);
            float gg = tanh_(gbuf[bu][512 + u]);
            float go = sig_(gbuf[bu][768 + u]);
            c2 = gf * c2 + gi * gg;
            hl2[p][bu][u] = (_Float16)(go * tanh_(c2));
        }
        __syncthreads();

        // ---- y = h2 @ W_lin.T + b_lin (waves 0..3) ----
        if (wv < 4) {
            vh4 hv = *(const vh4*)&hl2[p][ob][4 * lane];
            float s = (float)hv.x * wl0 + (float)hv.y * wl1
                    + (float)hv.z * wl2 + (float)hv.w * wl3;
            #pragma unroll
            for (int m = 32; m >= 1; m >>= 1) s += __shfl_xor(s, m, 64);
            if (lane == 0)
                out[(size_t)(b0 + ob) * 512 + t * 2 + oo] = s + blin;
        }

        // prefetch x for t+1 (wraps harmlessly at the end)
        const int tn = (t + 1) & (TSTEPS - 1);
        xv0 = *(const vf2*)(x + (size_t)(b0 + 0) * 512 + tn * 2);
        xv1 = *(const vf2*)(x + (size_t)(b0 + 1) * 512 + tn * 2);
    }
}

extern "C" void kernel_launch(void* const* d_in, const int* in_sizes, int n_in,
                              void* d_out, int out_size, void* d_ws, size_t ws_size,
                              hipStream_t stream) {
    const float* x     = (const float*)d_in[0];
    const float* W_ih1 = (const float*)d_in[1];
    const float* W_hh1 = (const float*)d_in[2];
    const float* b_ih1 = (const float*)d_in[3];
    const float* b_hh1 = (const float*)d_in[4];
    const float* W_ih2 = (const float*)d_in[5];
    const float* W_hh2 = (const float*)d_in[6];
    const float* b_ih2 = (const float*)d_in[7];
    const float* b_hh2 = (const float*)d_in[8];
    const float* W_lin = (const float*)d_in[9];
    const float* b_lin = (const float*)d_in[10];
    float* out = (float*)d_out;

    prep_kernel<<<256, 256, 0, stream>>>(W_ih1, W_hh1, b_ih1, b_hh1,
                                         W_ih2, W_hh2, b_ih2, b_hh2, d_ws);
    lstm_kernel<<<256, NT, 0, stream>>>(x, d_ws, W_lin, b_lin, out);
}

// Round 8
// 14105.077 us; speedup vs baseline: 1.0489x; 1.0489x over previous
//
#include <hip/hip_runtime.h>

// 2-layer LSTM (H=256, T=256, B=512, I=2) + linear head.
// 256 blocks x 1024 threads, 2 batch elements per block, t-loop in-kernel.
// Weight stream fp16: 96 logical chunks/step (chunk = 8 k x 1024 gate-rows,
// 16 B/thread). Parking: 16 chunks in VGPRs (vp0..vp15), 8 in LDS (128 KB),
// 72 streamed from L2 via a 4-buffer register pipeline (72 % 4 == 0 ->
// stable rotation phase each step). Occupancy contract (round-5/7 lesson):
// LDS = 140 KB makes 2 blocks/CU impossible AND amdgpu_waves_per_eu(4,4)
// pins the allocator at the 128-VGPR budget -> parked vh8 stay in registers
// (spill signature to watch: FETCH/WRITE blowing up to GB scale).
// h in LDS fp16 (same-address broadcast b128 reads, conflict-free), c in
// regs, 4 barriers/step, fdot2 via union sub-register views (no packs).
// Round-3 lesson: no cross-block exchange, ever.

typedef float vf2 __attribute__((ext_vector_type(2)));
typedef _Float16 vh2 __attribute__((ext_vector_type(2)));
typedef _Float16 vh4 __attribute__((ext_vector_type(4)));
typedef _Float16 vh8 __attribute__((ext_vector_type(8)));

#define NT 1024
#define TSTEPS 256
#define NCH 96            // logical chunks per step
#define NSTRM 72          // streamed chunks per step (others parked)
#define CHB 16384         // bytes per chunk = 1024 threads * 16 B
#define FS 393216         // fp32 table offset (floats) = 96*CHB/4

// park membership: ch%6==3 -> VGPR (16 chunks), ch%12==0 -> LDS (8 chunks).
// storage: streamed at [0..72) in logical order, VGPR-parked at [72..88),
// LDS-parked at [88..96), each in logical order.

__global__ void prep_kernel(const float* __restrict__ W_ih1,
                            const float* __restrict__ W_hh1,
                            const float* __restrict__ b_ih1,
                            const float* __restrict__ b_hh1,
                            const float* __restrict__ W_ih2,
                            const float* __restrict__ W_hh2,
                            const float* __restrict__ b_ih2,
                            const float* __restrict__ b_hh2,
                            void* __restrict__ ws) {
    const int stride = gridDim.x * blockDim.x;
    const int idx = blockIdx.x * blockDim.x + threadIdx.x;
    _Float16* wh = (_Float16*)ws;
    float* wf = (float*)ws;
    // logical chunk ch covers k = 8*ch..8*ch+7 for all 1024 gate-rows.
    // k<256: W_hh1 | k<512: W_ih2 | else W_hh2.
    for (int e = idx; e < NCH * 8192; e += stride) {
        int ch = e >> 13, rem = e & 8191, row = rem >> 3, i = rem & 7;
        int k = (ch << 3) + i;
        float v;
        if (k < 256)      v = W_hh1[row * 256 + k];
        else if (k < 512) v = W_ih2[row * 256 + (k - 256)];
        else              v = W_hh2[row * 256 + (k - 512)];
        int nV = (ch + 2) / 6;       // # VGPR-parked with ch' < ch
        int nL = (ch + 11) / 12;     // # LDS-parked with ch' < ch
        int pos;
        if ((ch % 6) == 3)       pos = 72 + nV;
        else if ((ch % 12) == 0) pos = 88 + nL;
        else                     pos = ch - nV - nL;
        wh[pos * 8192 + rem] = (_Float16)v;
    }
    for (int j = idx; j < 1024; j += stride) {
        wf[FS + j]        = W_ih1[j * 2 + 0];
        wf[FS + 1024 + j] = W_ih1[j * 2 + 1];
        wf[FS + 2048 + j] = b_ih1[j] + b_hh1[j];
        wf[FS + 3072 + j] = b_ih2[j] + b_hh2[j];
    }
}

__device__ __forceinline__ float sig_(float v) {
    return 1.f / (1.f + __expf(-v));
}
__device__ __forceinline__ float tanh_(float v) {
    return 1.f - 2.f / (__expf(2.f * v) + 1.f);
}
__device__ __forceinline__ float fdot2_(vh2 a, vh2 b, float c) {
#if __has_builtin(__builtin_amdgcn_fdot2)
    return __builtin_amdgcn_fdot2(a, b, c, false);
#else
    return c + (float)a.x * (float)b.x + (float)a.y * (float)b.y;
#endif
}

union W8 { vh8 v; vh2 p[4]; };

// streamed slot: consume BUF then refill it from the stream
#define US(BUF, HP, KL) { usec(BUF, HP, KL); loadc(BUF); }
// VGPR-parked slot
#define UP(VP, HP, KL)  { usec(VP, HP, KL); }
// LDS-parked slot
#define UL(S, HP, KL)   { vh8 t_ = *(const vh8*)&lds_park[S][t16]; usec(t_, HP, KL); }

__global__ __attribute__((amdgpu_flat_work_group_size(NT, NT),
                          amdgpu_waves_per_eu(4, 4)))
void lstm_kernel(
    const float* __restrict__ x,      // (512, 256, 2)
    const void* __restrict__ ws,
    const float* __restrict__ W_lin,  // (2, 256)
    const float* __restrict__ b_lin,  // (2,)
    float* __restrict__ out)          // (512, 256, 2)
{
    __shared__ float gbuf[2][1024];            // gate preacts [batch][row]
    __shared__ _Float16 hl1[2][2][256];        // h1 [parity][batch][unit]
    __shared__ _Float16 hl2[2][2][256];        // h2
    __shared__ char lds_park[8][CHB];          // 8 LDS-parked chunks (128 KB)

    const int tid = threadIdx.x;
    const int j = tid;                         // owned gate-row
    const int u = tid & 255, bu = (tid >> 8) & 1;
    const int b0 = blockIdx.x * 2;
    const char* wstream = (const char*)ws;
    const float* wf = (const float*)ws;

    const float wx0 = wf[FS + j], wx1 = wf[FS + 1024 + j];
    const float bj1 = wf[FS + 2048 + j], bj2 = wf[FS + 3072 + j];

    // y-head: waves 0..3 -> (batch ob, output oo); lane covers 4 units
    const int lane = tid & 63, wv = tid >> 6;
    const int ob = (wv >> 1) & 1, oo = wv & 1;
    const float wl0 = W_lin[oo * 256 + 4 * lane + 0];
    const float wl1 = W_lin[oo * 256 + 4 * lane + 1];
    const float wl2 = W_lin[oo * 256 + 4 * lane + 2];
    const float wl3 = W_lin[oo * 256 + 4 * lane + 3];
    const float blin = b_lin[oo];

    for (int i = tid; i < 2 * 2 * 256; i += NT) {
        ((_Float16*)hl1)[i] = (_Float16)0.f;
        ((_Float16*)hl2)[i] = (_Float16)0.f;
    }

    float c1 = 0.f, c2 = 0.f;
    vf2 xv0 = *(const vf2*)(x + (size_t)(b0 + 0) * 512);
    vf2 xv1 = *(const vf2*)(x + (size_t)(b0 + 1) * 512);

    const int t16 = tid * 16;
    int sp = 0;                                // uniform stream byte offset
    float acc0, acc1;

    auto loadc = [&](vh8& dst) {
        dst = *(const vh8*)(wstream + sp + t16);
        sp += CHB;
        if (sp == NSTRM * CHB) sp = 0;
    };
    auto usec = [&](vh8 w, const _Float16 (*hp)[256], int k0) {
        W8 uw; uw.v = w;
        W8 ua; ua.v = *(const vh8*)&hp[0][k0];
        W8 ub; ub.v = *(const vh8*)&hp[1][k0];
        acc0 = fdot2_(uw.p[0], ua.p[0], acc0);
        acc0 = fdot2_(uw.p[1], ua.p[1], acc0);
        acc0 = fdot2_(uw.p[2], ua.p[2], acc0);
        acc0 = fdot2_(uw.p[3], ua.p[3], acc0);
        acc1 = fdot2_(uw.p[0], ub.p[0], acc1);
        acc1 = fdot2_(uw.p[1], ub.p[1], acc1);
        acc1 = fdot2_(uw.p[2], ub.p[2], acc1);
        acc1 = fdot2_(uw.p[3], ub.p[3], acc1);
    };

    // park 16 chunks in VGPRs (positions 72..87) and 8 in LDS (88..95)
    #define LDP(P) (*(const vh8*)(wstream + (size_t)(P) * CHB + t16))
    const vh8 vp0  = LDP(72), vp1  = LDP(73), vp2  = LDP(74), vp3  = LDP(75);
    const vh8 vp4  = LDP(76), vp5  = LDP(77), vp6  = LDP(78), vp7  = LDP(79);
    const vh8 vp8  = LDP(80), vp9  = LDP(81), vp10 = LDP(82), vp11 = LDP(83);
    const vh8 vp12 = LDP(84), vp13 = LDP(85), vp14 = LDP(86), vp15 = LDP(87);
    #pragma unroll
    for (int s = 0; s < 8; ++s)
        *(vh8*)&lds_park[s][t16] = LDP(88 + s);
    #undef LDP

    vh8 bA, bB, bC, bD;
    loadc(bA); loadc(bB); loadc(bC); loadc(bD);
    __syncthreads();

    #pragma unroll 1
    for (int t = 0; t < TSTEPS; ++t) {
        const int p = t & 1, pm = p ^ 1;
        const _Float16 (*hpA)[256] = hl1[pm];  // h1(t-1)
        const _Float16 (*hpB)[256] = hl1[p];   // h1(t)
        const _Float16 (*hpC)[256] = hl2[pm];  // h2(t-1)

        // ---- layer 1 gates: b1 + Wih1*x_t + Whh1*h1(t-1) [ch 0..31] ----
        acc0 = bj1 + wx0 * xv0.x + wx1 * xv0.y;
        acc1 = bj1 + wx0 * xv1.x + wx1 * xv1.y;
        UL(0,hpA,0)
        US(bA,hpA,8)    US(bB,hpA,16)
        UP(vp0,hpA,24)
        US(bC,hpA,32)   US(bD,hpA,40)  US(bA,hpA,48)  US(bB,hpA,56)
        US(bC,hpA,64)
        UP(vp1,hpA,72)
        US(bD,hpA,80)   US(bA,hpA,88)
        UL(1,hpA,96)
        US(bB,hpA,104)  US(bC,hpA,112)
        UP(vp2,hpA,120)
        US(bD,hpA,128)  US(bA,hpA,136) US(bB,hpA,144) US(bC,hpA,152)
        US(bD,hpA,160)
        UP(vp3,hpA,168)
        US(bA,hpA,176)  US(bB,hpA,184)
        UL(2,hpA,192)
        US(bC,hpA,200)  US(bD,hpA,208)
        UP(vp4,hpA,216)
        US(bA,hpA,224)  US(bB,hpA,232) US(bC,hpA,240) US(bD,hpA,248)
        gbuf[0][j] = acc0; gbuf[1][j] = acc1;
        __syncthreads();

        // ---- layer 1 cell update (threads 0..511: unit u, batch bu) ----
        if (tid < 512) {
            float gi = sig_(gbuf[bu][u]);
            float gf = sig_(gbuf[bu][256 + u]);
            float gg = tanh_(gbuf[bu][512 + u]);
            float go = sig_(gbuf[bu][768 + u]);
            c1 = gf * c1 + gi * gg;
            hl1[p][bu][u] = (_Float16)(go * tanh_(c1));
        }
        __syncthreads();

        // ---- layer 2 gates: b2 + Wih2*h1(t) [ch 32..63] + Whh2*h2(t-1) [64..95] ----
        acc0 = bj2; acc1 = bj2;
        US(bA,hpB,0)
        UP(vp5,hpB,8)
        US(bB,hpB,16)   US(bC,hpB,24)
        UL(3,hpB,32)
        US(bD,hpB,40)   US(bA,hpB,48)
        UP(vp6,hpB,56)
        US(bB,hpB,64)   US(bC,hpB,72)  US(bD,hpB,80)  US(bA,hpB,88)
        US(bB,hpB,96)
        UP(vp7,hpB,104)
        US(bC,hpB,112)  US(bD,hpB,120)
        UL(4,hpB,128)
        US(bA,hpB,136)  US(bB,hpB,144)
        UP(vp8,hpB,152)
        US(bC,hpB,160)  US(bD,hpB,168) US(bA,hpB,176) US(bB,hpB,184)
        US(bC,hpB,192)
        UP(vp9,hpB,200)
        US(bD,hpB,208)  US(bA,hpB,216)
        UL(5,hpB,224)
        US(bB,hpB,232)  US(bC,hpB,240)
        UP(vp10,hpB,248)
        US(bD,hpC,0)    US(bA,hpC,8)   US(bB,hpC,16)  US(bC,hpC,24)
        US(bD,hpC,32)
        UP(vp11,hpC,40)
        US(bA,hpC,48)   US(bB,hpC,56)
        UL(6,hpC,64)
        US(bC,hpC,72)   US(bD,hpC,80)
        UP(vp12,hpC,88)
        US(bA,hpC,96)   US(bB,hpC,104) US(bC,hpC,112) US(bD,hpC,120)
        US(bA,hpC,128)
        UP(vp13,hpC,136)
        US(bB,hpC,144)  US(bC,hpC,152)
        UL(7,hpC,160)
        US(bD,hpC,168)  US(bA,hpC,176)
        UP(vp14,hpC,184)
        US(bB,hpC,192)  US(bC,hpC,200) US(bD,hpC,208) US(bA,hpC,216)
        US(bB,hpC,224)
        UP(vp15,hpC,232)
        US(bC,hpC,240)  US(bD,hpC,248)
        gbuf[0][j] = acc0; gbuf[1][j] = acc1;
        __syncthreads();

        // ---- layer 2 cell update ----
        if (tid < 512) {
            float gi = sig_(gbuf[bu][u]);
            float gf = sig_(gbuf[bu][256 + u]);
            float gg = tanh_(gbuf[bu][512 + u]);
            float go = sig_(gbuf[bu][768 + u]);
            c2 = gf * c2 + gi * gg;
            hl2[p][bu][u] = (_Float16)(go * tanh_(c2));
        }
        __syncthreads();

        // ---- y = h2 @ W_lin.T + b_lin (waves 0..3) ----
        if (wv < 4) {
            vh4 hv = *(const vh4*)&hl2[p][ob][4 * lane];
            float s = (float)hv.x * wl0 + (float)hv.y * wl1
                    + (float)hv.z * wl2 + (float)hv.w * wl3;
            #pragma unroll
            for (int m = 32; m >= 1; m >>= 1) s += __shfl_xor(s, m, 64);
            if (lane == 0)
                out[(size_t)(b0 + ob) * 512 + t * 2 + oo] = s + blin;
        }

        // prefetch x for t+1 (wraps harmlessly at the end)
        const int tn = (t + 1) & (TSTEPS - 1);
        xv0 = *(const vf2*)(x + (size_t)(b0 + 0) * 512 + tn * 2);
        xv1 = *(const vf2*)(x + (size_t)(b0 + 1) * 512 + tn * 2);
    }
}

extern "C" void kernel_launch(void* const* d_in, const int* in_sizes, int n_in,
                              void* d_out, int out_size, void* d_ws, size_t ws_size,
                              hipStream_t stream) {
    const float* x     = (const float*)d_in[0];
    const float* W_ih1 = (const float*)d_in[1];
    const float* W_hh1 = (const float*)d_in[2];
    const float* b_ih1 = (const float*)d_in[3];
    const float* b_hh1 = (const float*)d_in[4];
    const float* W_ih2 = (const float*)d_in[5];
    const float* W_hh2 = (const float*)d_in[6];
    const float* b_ih2 = (const float*)d_in[7];
    const float* b_hh2 = (const float*)d_in[8];
    const float* W_lin = (const float*)d_in[9];
    const float* b_lin = (const float*)d_in[10];
    float* out = (float*)d_out;

    prep_kernel<<<256, 256, 0, stream>>>(W_ih1, W_hh1, b_ih1, b_hh1,
                                         W_ih2, W_hh2, b_ih2, b_hh2, d_ws);
    lstm_kernel<<<256, NT, 0, stream>>>(x, d_ws, W_lin, b_lin, out);
}

// Round 9
// 11696.424 us; speedup vs baseline: 1.2649x; 1.2059x over previous
//
#include <hip/hip_runtime.h>

// 2-layer LSTM (H=256, T=256, B=512, I=2) + linear head.
// 256 blocks x 1024 threads, 2 batches/block, t-loop in-kernel.
// Weight stream fp16: 96 logical chunks/step (chunk = 8 k x 1024 gate-rows,
// 16 B/thread). Parking: 4 chunks in VGPRs (16 regs; allocator caps this
// kernel at 64 VGPRs - rounds 5/7/8 proved ANY bigger park spills to
// scratch and thrashes L2) + 8 chunks in LDS (128 KB, cannot spill).
// 84 streamed via 4-buffer register pipeline (84 % 4 == 0 -> fixed
// rotation phase; explicit 96-slot unrolled schedule).
// Barriers are lgkmcnt-only (inline asm): all global loads are
// thread-private and `out` is never read back, so the vmcnt(0) drain that
// __syncthreads() would impose (m97 barrier-drain) is unnecessary -> the
// weight-stream prefetch stays in flight across barriers.
// h in LDS fp16 (same-address broadcast reads), c in regs, fdot2 via
// union sub-register views. Round-3 lesson: no cross-block exchange.

typedef float vf2 __attribute__((ext_vector_type(2)));
typedef _Float16 vh2 __attribute__((ext_vector_type(2)));
typedef _Float16 vh4 __attribute__((ext_vector_type(4)));
typedef _Float16 vh8 __attribute__((ext_vector_type(8)));

#define NT 1024
#define TSTEPS 256
#define NCH 96            // logical chunks per step
#define NSTRM 84          // streamed chunks per step
#define CHB 16384         // bytes per chunk = 1024 threads * 16 B
#define FS 393216         // fp32 table offset (floats) = 96*CHB/4

// parked: ch%8==4 (12 chunks). Of those, ch%24==4 -> VGPR ({4,28,52,76}),
// else LDS ({12,20,36,44,60,68,84,92}).
// storage: streamed at [0..84) in logical order; VGPR parks at 84..87;
// LDS parks at 88..95.

__global__ void prep_kernel(const float* __restrict__ W_ih1,
                            const float* __restrict__ W_hh1,
                            const float* __restrict__ b_ih1,
                            const float* __restrict__ b_hh1,
                            const float* __restrict__ W_ih2,
                            const float* __restrict__ W_hh2,
                            const float* __restrict__ b_ih2,
                            const float* __restrict__ b_hh2,
                            void* __restrict__ ws) {
    const int stride = gridDim.x * blockDim.x;
    const int idx = blockIdx.x * blockDim.x + threadIdx.x;
    _Float16* wh = (_Float16*)ws;
    float* wf = (float*)ws;
    // logical chunk ch covers k = 8*ch..8*ch+7 for all 1024 gate-rows.
    // k<256: W_hh1 | k<512: W_ih2 | else W_hh2.
    for (int e = idx; e < NCH * 8192; e += stride) {
        int ch = e >> 13, rem = e & 8191, row = rem >> 3, i = rem & 7;
        int k = (ch << 3) + i;
        float v;
        if (k < 256)      v = W_hh1[row * 256 + k];
        else if (k < 512) v = W_ih2[row * 256 + (k - 256)];
        else              v = W_hh2[row * 256 + (k - 512)];
        int nP = (ch + 3) >> 3;          // parked chunks with ch' < ch
        int pos;
        if ((ch & 7) == 4) {
            if (ch % 24 == 4) pos = 84 + ch / 24;              // VGPR park
            else {
                int nV = (ch + 19) / 24;                       // VGPR parks < ch
                pos = 88 + (nP - nV);                          // LDS park
            }
        } else {
            pos = ch - nP;                                     // streamed
        }
        wh[pos * 8192 + rem] = (_Float16)v;
    }
    for (int j = idx; j < 1024; j += stride) {
        wf[FS + j]        = W_ih1[j * 2 + 0];
        wf[FS + 1024 + j] = W_ih1[j * 2 + 1];
        wf[FS + 2048 + j] = b_ih1[j] + b_hh1[j];
        wf[FS + 3072 + j] = b_ih2[j] + b_hh2[j];
    }
}

__device__ __forceinline__ float sig_(float v) {
    return 1.f / (1.f + __expf(-v));
}
__device__ __forceinline__ float tanh_(float v) {
    return 1.f - 2.f / (__expf(2.f * v) + 1.f);
}
__device__ __forceinline__ float fdot2_(vh2 a, vh2 b, float c) {
#if __has_builtin(__builtin_amdgcn_fdot2)
    return __builtin_amdgcn_fdot2(a, b, c, false);
#else
    return c + (float)a.x * (float)b.x + (float)a.y * (float)b.y;
#endif
}

union W8 { vh8 v; vh2 p[4]; };

// lgkm-only barrier: LDS writes drained, weight-stream vmem stays in flight.
#define BARRIER() __asm__ volatile("s_waitcnt lgkmcnt(0)\ns_barrier" ::: "memory")

// streamed slot: consume BUF then refill it from the stream
#define US(BUF, HP, KL) { usec(BUF, HP, KL); loadc(BUF); }
// VGPR-parked slot
#define UP(VP, HP, KL)  { usec(VP, HP, KL); }
// LDS-parked slot
#define UL(S, HP, KL)   { vh8 t_ = *(const vh8*)&lds_park[S][t16]; usec(t_, HP, KL); }

__global__ __launch_bounds__(NT, 4) void lstm_kernel(
    const float* __restrict__ x,      // (512, 256, 2)
    const void* __restrict__ ws,
    const float* __restrict__ W_lin,  // (2, 256)
    const float* __restrict__ b_lin,  // (2,)
    float* __restrict__ out)          // (512, 256, 2)
{
    __shared__ float gbuf[2][1024];            // gate preacts [batch][row]
    __shared__ _Float16 hl1[2][2][256];        // h1 [parity][batch][unit]
    __shared__ _Float16 hl2[2][2][256];        // h2
    __shared__ char lds_park[8][CHB];          // 8 LDS-parked chunks (128 KB)

    const int tid = threadIdx.x;
    const int j = tid;                         // owned gate-row
    const int u = tid & 255, bu = (tid >> 8) & 1;
    const int b0 = blockIdx.x * 2;
    const char* wstream = (const char*)ws;
    const float* wf = (const float*)ws;

    const float wx0 = wf[FS + j], wx1 = wf[FS + 1024 + j];
    const float bj1 = wf[FS + 2048 + j], bj2 = wf[FS + 3072 + j];

    // y-head: waves 0..3 -> (batch ob, output oo); lane covers 4 units
    const int lane = tid & 63, wv = tid >> 6;
    const int ob = (wv >> 1) & 1, oo = wv & 1;
    const float wl0 = W_lin[oo * 256 + 4 * lane + 0];
    const float wl1 = W_lin[oo * 256 + 4 * lane + 1];
    const float wl2 = W_lin[oo * 256 + 4 * lane + 2];
    const float wl3 = W_lin[oo * 256 + 4 * lane + 3];
    const float blin = b_lin[oo];

    for (int i = tid; i < 2 * 2 * 256; i += NT) {
        ((_Float16*)hl1)[i] = (_Float16)0.f;
        ((_Float16*)hl2)[i] = (_Float16)0.f;
    }

    float c1 = 0.f, c2 = 0.f;
    vf2 xv0 = *(const vf2*)(x + (size_t)(b0 + 0) * 512);
    vf2 xv1 = *(const vf2*)(x + (size_t)(b0 + 1) * 512);

    const int t16 = tid * 16;
    int sp = 0;                                // uniform stream byte offset
    float acc0, acc1;

    auto loadc = [&](vh8& dst) {
        dst = *(const vh8*)(wstream + sp + t16);
        sp += CHB;
        if (sp == NSTRM * CHB) sp = 0;
    };
    auto usec = [&](vh8 w, const _Float16 (*hp)[256], int k0) {
        W8 uw; uw.v = w;
        W8 ua; ua.v = *(const vh8*)&hp[0][k0];
        W8 ub; ub.v = *(const vh8*)&hp[1][k0];
        acc0 = fdot2_(uw.p[0], ua.p[0], acc0);
        acc0 = fdot2_(uw.p[1], ua.p[1], acc0);
        acc0 = fdot2_(uw.p[2], ua.p[2], acc0);
        acc0 = fdot2_(uw.p[3], ua.p[3], acc0);
        acc1 = fdot2_(uw.p[0], ub.p[0], acc1);
        acc1 = fdot2_(uw.p[1], ub.p[1], acc1);
        acc1 = fdot2_(uw.p[2], ub.p[2], acc1);
        acc1 = fdot2_(uw.p[3], ub.p[3], acc1);
    };

    // park 4 chunks in VGPRs (positions 84..87) and 8 in LDS (88..95)
    #define LDP(P) (*(const vh8*)(wstream + (size_t)(P) * CHB + t16))
    const vh8 vp0 = LDP(84), vp1 = LDP(85), vp2 = LDP(86), vp3 = LDP(87);
    #pragma unroll
    for (int s = 0; s < 8; ++s)
        *(vh8*)&lds_park[s][t16] = LDP(88 + s);
    #undef LDP

    vh8 bA, bB, bC, bD;
    loadc(bA); loadc(bB); loadc(bC); loadc(bD);
    __syncthreads();   // init barrier (outside hot loop, full drain is fine)

    #pragma unroll 1
    for (int t = 0; t < TSTEPS; ++t) {
        const int p = t & 1, pm = p ^ 1;
        const _Float16 (*hpA)[256] = hl1[pm];  // h1(t-1)
        const _Float16 (*hpB)[256] = hl1[p];   // h1(t)
        const _Float16 (*hpC)[256] = hl2[pm];  // h2(t-1)

        // ---- layer 1 gates: b1 + Wih1*x_t + Whh1*h1(t-1) [ch 0..31] ----
        // parked slots: 4 (vp0), 12 (lds0), 20 (lds1), 28 (vp1)
        acc0 = bj1 + wx0 * xv0.x + wx1 * xv0.y;
        acc1 = bj1 + wx0 * xv1.x + wx1 * xv1.y;
        US(bA,hpA,0)    US(bB,hpA,8)   US(bC,hpA,16)  US(bD,hpA,24)
        UP(vp0,hpA,32)
        US(bA,hpA,40)   US(bB,hpA,48)  US(bC,hpA,56)  US(bD,hpA,64)
        US(bA,hpA,72)   US(bB,hpA,80)  US(bC,hpA,88)
        UL(0,hpA,96)
        US(bD,hpA,104)  US(bA,hpA,112) US(bB,hpA,120) US(bC,hpA,128)
        US(bD,hpA,136)  US(bA,hpA,144) US(bB,hpA,152)
        UL(1,hpA,160)
        US(bC,hpA,168)  US(bD,hpA,176) US(bA,hpA,184) US(bB,hpA,192)
        US(bC,hpA,200)  US(bD,hpA,208) US(bA,hpA,216)
        UP(vp1,hpA,224)
        US(bB,hpA,232)  US(bC,hpA,240) US(bD,hpA,248)
        gbuf[0][j] = acc0; gbuf[1][j] = acc1;
        BARRIER();

        // ---- layer 1 cell update (threads 0..511: unit u, batch bu) ----
        if (tid < 512) {
            float gi = sig_(gbuf[bu][u]);
            float gf = sig_(gbuf[bu][256 + u]);
            float gg = tanh_(gbuf[bu][512 + u]);
            float go = sig_(gbuf[bu][768 + u]);
            c1 = gf * c1 + gi * gg;
            hl1[p][bu][u] = (_Float16)(go * tanh_(c1));
        }
        BARRIER();

        // ---- layer 2 gates: b2 + Wih2*h1(t) [ch 32..63] + Whh2*h2(t-1) [64..95] ----
        // parked: 36 (lds2), 44 (lds3), 52 (vp2), 60 (lds4),
        //         68 (lds5), 76 (vp3), 84 (lds6), 92 (lds7)
        acc0 = bj2; acc1 = bj2;
        US(bA,hpB,0)    US(bB,hpB,8)   US(bC,hpB,16)  US(bD,hpB,24)
        UL(2,hpB,32)
        US(bA,hpB,40)   US(bB,hpB,48)  US(bC,hpB,56)  US(bD,hpB,64)
        US(bA,hpB,72)   US(bB,hpB,80)  US(bC,hpB,88)
        UL(3,hpB,96)
        US(bD,hpB,104)  US(bA,hpB,112) US(bB,hpB,120) US(bC,hpB,128)
        US(bD,hpB,136)  US(bA,hpB,144) US(bB,hpB,152)
        UP(vp2,hpB,160)
        US(bC,hpB,168)  US(bD,hpB,176) US(bA,hpB,184) US(bB,hpB,192)
        US(bC,hpB,200)  US(bD,hpB,208) US(bA,hpB,216)
        UL(4,hpB,224)
        US(bB,hpB,232)  US(bC,hpB,240) US(bD,hpB,248)
        US(bA,hpC,0)    US(bB,hpC,8)   US(bC,hpC,16)  US(bD,hpC,24)
        UL(5,hpC,32)
        US(bA,hpC,40)   US(bB,hpC,48)  US(bC,hpC,56)  US(bD,hpC,64)
        US(bA,hpC,72)   US(bB,hpC,80)  US(bC,hpC,88)
        UP(vp3,hpC,96)
        US(bD,hpC,104)  US(bA,hpC,112) US(bB,hpC,120) US(bC,hpC,128)
        US(bD,hpC,136)  US(bA,hpC,144) US(bB,hpC,152)
        UL(6,hpC,160)
        US(bC,hpC,168)  US(bD,hpC,176) US(bA,hpC,184) US(bB,hpC,192)
        US(bC,hpC,200)  US(bD,hpC,208) US(bA,hpC,216)
        UL(7,hpC,224)
        US(bB,hpC,232)  US(bC,hpC,240) US(bD,hpC,248)
        gbuf[0][j] = acc0; gbuf[1][j] = acc1;
        BARRIER();

        // ---- layer 2 cell update ----
        if (tid < 512) {
            float gi = sig_(gbuf[bu][u]);
            float gf = sig_(gbuf[bu][256 + u]);
            float gg = tanh_(gbuf[bu][512 + u]);
            float go = sig_(gbuf[bu][768 + u]);
            c2 = gf * c2 + gi * gg;
            hl2[p][bu][u] = (_Float16)(go * tanh_(c2));
        }
        BARRIER();

        // ---- y = h2 @ W_lin.T + b_lin (waves 0..3) ----
        if (wv < 4) {
            vh4 hv = *(const vh4*)&hl2[p][ob][4 * lane];
            float s = (float)hv.x * wl0 + (float)hv.y * wl1
                    + (float)hv.z * wl2 + (float)hv.w * wl3;
            #pragma unroll
            for (int m = 32; m >= 1; m >>= 1) s += __shfl_xor(s, m, 64);
            if (lane == 0)
                out[(size_t)(b0 + ob) * 512 + t * 2 + oo] = s + blin;
        }

        // prefetch x for t+1 (wraps harmlessly at the end)
        const int tn = (t + 1) & (TSTEPS - 1);
        xv0 = *(const vf2*)(x + (size_t)(b0 + 0) * 512 + tn * 2);
        xv1 = *(const vf2*)(x + (size_t)(b0 + 1) * 512 + tn * 2);
    }
}

extern "C" void kernel_launch(void* const* d_in, const int* in_sizes, int n_in,
                              void* d_out, int out_size, void* d_ws, size_t ws_size,
                              hipStream_t stream) {
    const float* x     = (const float*)d_in[0];
    const float* W_ih1 = (const float*)d_in[1];
    const float* W_hh1 = (const float*)d_in[2];
    const float* b_ih1 = (const float*)d_in[3];
    const float* b_hh1 = (const float*)d_in[4];
    const float* W_ih2 = (const float*)d_in[5];
    const float* W_hh2 = (const float*)d_in[6];
    const float* b_ih2 = (const float*)d_in[7];
    const float* b_hh2 = (const float*)d_in[8];
    const float* W_lin = (const float*)d_in[9];
    const float* b_lin = (const float*)d_in[10];
    float* out = (float*)d_out;

    prep_kernel<<<256, 256, 0, stream>>>(W_ih1, W_hh1, b_ih1, b_hh1,
                                         W_ih2, W_hh2, b_ih2, b_hh2, d_ws);
    lstm_kernel<<<256, NT, 0, stream>>>(x, d_ws, W_lin, b_lin, out);
}

// Round 10
// 11637.251 us; speedup vs baseline: 1.2714x; 1.0051x over previous
//
#include <hip/hip_runtime.h>

// 2-layer LSTM (H=256, T=256, B=512, I=2) + linear head.
// 256 blocks x 1024 threads, 2 batches/block, t-loop in-kernel.
// Weight stream fp16: 96 logical chunks/step (chunk = 8 k x 1024 gate-rows,
// 16 B/thread). 8 chunks parked in LDS (128 KB — LDS cannot spill);
// 88 streamed from L2 via a 4-buffer register pipeline (88 % 4 == 0 ->
// rotation phase identical every step; explicit 96-slot schedule).
// NO VGPR parking: rounds 5/7/8/9 proved the allocator pins this kernel at
// 64 VGPRs and spills ANY long-lived parked set to scratch (signature:
// FETCH/WRITE at GB scale). Round-6 register shape (44 VGPR) is kept.
// Barriers are lgkmcnt-only (inline asm, correctness proven in round 9):
// all global loads are thread-private and `out` is never read back, so the
// vmcnt(0) drain __syncthreads would impose is unnecessary -> the weight
// prefetch queue stays in flight across barriers.
// h in LDS fp16 (same-address broadcast reads, conflict-free), c in regs,
// fdot2 via union sub-register views (no pack VALU).
// Round-3 lesson: no cross-block exchange, ever.

typedef float vf2 __attribute__((ext_vector_type(2)));
typedef _Float16 vh2 __attribute__((ext_vector_type(2)));
typedef _Float16 vh4 __attribute__((ext_vector_type(4)));
typedef _Float16 vh8 __attribute__((ext_vector_type(8)));

#define NT 1024
#define TSTEPS 256
#define NCH 96            // logical chunks per step
#define NSTRM 88          // streamed chunks per step
#define CHB 16384         // bytes per chunk = 1024 threads * 16 B
#define FS 393216         // fp32 table offset (floats) = 96*CHB/4

// parked: ch % 12 == 5 -> LDS ({5,17,29,41,53,65,77,89}).
// storage: streamed at [0..88) in logical order; LDS parks at [88..96)
// (ch/12 gives the slot).

__global__ void prep_kernel(const float* __restrict__ W_ih1,
                            const float* __restrict__ W_hh1,
                            const float* __restrict__ b_ih1,
                            const float* __restrict__ b_hh1,
                            const float* __restrict__ W_ih2,
                            const float* __restrict__ W_hh2,
                            const float* __restrict__ b_ih2,
                            const float* __restrict__ b_hh2,
                            void* __restrict__ ws) {
    const int stride = gridDim.x * blockDim.x;
    const int idx = blockIdx.x * blockDim.x + threadIdx.x;
    _Float16* wh = (_Float16*)ws;
    float* wf = (float*)ws;
    // logical chunk ch covers k = 8*ch..8*ch+7 for all 1024 gate-rows.
    // k<256: W_hh1 | k<512: W_ih2 | else W_hh2.
    for (int e = idx; e < NCH * 8192; e += stride) {
        int ch = e >> 13, rem = e & 8191, row = rem >> 3, i = rem & 7;
        int k = (ch << 3) + i;
        float v;
        if (k < 256)      v = W_hh1[row * 256 + k];
        else if (k < 512) v = W_ih2[row * 256 + (k - 256)];
        else              v = W_hh2[row * 256 + (k - 512)];
        int nP = (ch + 6) / 12;          // parked chunks with ch' < ch
        int pos = (ch % 12 == 5) ? (88 + ch / 12) : (ch - nP);
        wh[pos * 8192 + rem] = (_Float16)v;
    }
    for (int j = idx; j < 1024; j += stride) {
        wf[FS + j]        = W_ih1[j * 2 + 0];
        wf[FS + 1024 + j] = W_ih1[j * 2 + 1];
        wf[FS + 2048 + j] = b_ih1[j] + b_hh1[j];
        wf[FS + 3072 + j] = b_ih2[j] + b_hh2[j];
    }
}

__device__ __forceinline__ float sig_(float v) {
    return 1.f / (1.f + __expf(-v));
}
__device__ __forceinline__ float tanh_(float v) {
    return 1.f - 2.f / (__expf(2.f * v) + 1.f);
}
__device__ __forceinline__ float fdot2_(vh2 a, vh2 b, float c) {
#if __has_builtin(__builtin_amdgcn_fdot2)
    return __builtin_amdgcn_fdot2(a, b, c, false);
#else
    return c + (float)a.x * (float)b.x + (float)a.y * (float)b.y;
#endif
}

union W8 { vh8 v; vh2 p[4]; };

// lgkm-only barrier: LDS drained, weight-stream vmem stays in flight.
#define BARRIER() __asm__ volatile("s_waitcnt lgkmcnt(0)\ns_barrier" ::: "memory")

// streamed slot: consume BUF then refill it from the stream
#define US(BUF, HP, KL) { usec(BUF, HP, KL); loadc(BUF); }
// LDS-parked slot
#define UL(S, HP, KL)   { vh8 t_ = *(const vh8*)&lds_park[S][t16]; usec(t_, HP, KL); }

__global__ __launch_bounds__(NT, 4) void lstm_kernel(
    const float* __restrict__ x,      // (512, 256, 2)
    const void* __restrict__ ws,
    const float* __restrict__ W_lin,  // (2, 256)
    const float* __restrict__ b_lin,  // (2,)
    float* __restrict__ out)          // (512, 256, 2)
{
    __shared__ float gbuf[2][1024];            // gate preacts [batch][row]
    __shared__ _Float16 hl1[2][2][256];        // h1 [parity][batch][unit]
    __shared__ _Float16 hl2[2][2][256];        // h2
    __shared__ char lds_park[8][CHB];          // 8 LDS-parked chunks (128 KB)

    const int tid = threadIdx.x;
    const int j = tid;                         // owned gate-row
    const int u = tid & 255, bu = (tid >> 8) & 1;
    const int b0 = blockIdx.x * 2;
    const char* wstream = (const char*)ws;
    const float* wf = (const float*)ws;

    const float wx0 = wf[FS + j], wx1 = wf[FS + 1024 + j];
    const float bj1 = wf[FS + 2048 + j], bj2 = wf[FS + 3072 + j];

    // y-head: waves 0..3 -> (batch ob, output oo); lane covers 4 units
    const int lane = tid & 63, wv = tid >> 6;
    const int ob = (wv >> 1) & 1, oo = wv & 1;
    const float wl0 = W_lin[oo * 256 + 4 * lane + 0];
    const float wl1 = W_lin[oo * 256 + 4 * lane + 1];
    const float wl2 = W_lin[oo * 256 + 4 * lane + 2];
    const float wl3 = W_lin[oo * 256 + 4 * lane + 3];
    const float blin = b_lin[oo];

    for (int i = tid; i < 2 * 2 * 256; i += NT) {
        ((_Float16*)hl1)[i] = (_Float16)0.f;
        ((_Float16*)hl2)[i] = (_Float16)0.f;
    }

    float c1 = 0.f, c2 = 0.f;
    vf2 xv0 = *(const vf2*)(x + (size_t)(b0 + 0) * 512);
    vf2 xv1 = *(const vf2*)(x + (size_t)(b0 + 1) * 512);

    const int t16 = tid * 16;
    int sp = 0;                                // uniform stream byte offset
    float acc0, acc1;

    auto loadc = [&](vh8& dst) {
        dst = *(const vh8*)(wstream + sp + t16);
        sp += CHB;
        if (sp == NSTRM * CHB) sp = 0;
    };
    auto usec = [&](vh8 w, const _Float16 (*hp)[256], int k0) {
        W8 uw; uw.v = w;
        W8 ua; ua.v = *(const vh8*)&hp[0][k0];
        W8 ub; ub.v = *(const vh8*)&hp[1][k0];
        acc0 = fdot2_(uw.p[0], ua.p[0], acc0);
        acc0 = fdot2_(uw.p[1], ua.p[1], acc0);
        acc0 = fdot2_(uw.p[2], ua.p[2], acc0);
        acc0 = fdot2_(uw.p[3], ua.p[3], acc0);
        acc1 = fdot2_(uw.p[0], ub.p[0], acc1);
        acc1 = fdot2_(uw.p[1], ub.p[1], acc1);
        acc1 = fdot2_(uw.p[2], ub.p[2], acc1);
        acc1 = fdot2_(uw.p[3], ub.p[3], acc1);
    };

    // stage the 8 LDS-parked chunks (positions 88..95)
    #pragma unroll
    for (int s = 0; s < 8; ++s)
        *(vh8*)&lds_park[s][t16] =
            *(const vh8*)(wstream + (size_t)(88 + s) * CHB + t16);

    vh8 bA, bB, bC, bD;
    loadc(bA); loadc(bB); loadc(bC); loadc(bD);
    __syncthreads();   // init barrier (full drain once is fine)

    #pragma unroll 1
    for (int t = 0; t < TSTEPS; ++t) {
        const int p = t & 1, pm = p ^ 1;
        const _Float16 (*hpA)[256] = hl1[pm];  // h1(t-1)
        const _Float16 (*hpB)[256] = hl1[p];   // h1(t)
        const _Float16 (*hpC)[256] = hl2[pm];  // h2(t-1)

        // ---- layer 1 gates: b1 + Wih1*x_t + Whh1*h1(t-1) [ch 0..31] ----
        // parked slots here: ch 5 (L0 @k40), ch 17 (L1 @k136), ch 29 (L2 @k232)
        acc0 = bj1 + wx0 * xv0.x + wx1 * xv0.y;
        acc1 = bj1 + wx0 * xv1.x + wx1 * xv1.y;
        US(bA,hpA,0)    US(bB,hpA,8)   US(bC,hpA,16)  US(bD,hpA,24)
        US(bA,hpA,32)
        UL(0,hpA,40)
        US(bB,hpA,48)   US(bC,hpA,56)  US(bD,hpA,64)  US(bA,hpA,72)
        US(bB,hpA,80)   US(bC,hpA,88)  US(bD,hpA,96)  US(bA,hpA,104)
        US(bB,hpA,112)  US(bC,hpA,120) US(bD,hpA,128)
        UL(1,hpA,136)
        US(bA,hpA,144)  US(bB,hpA,152) US(bC,hpA,160) US(bD,hpA,168)
        US(bA,hpA,176)  US(bB,hpA,184) US(bC,hpA,192) US(bD,hpA,200)
        US(bA,hpA,208)  US(bB,hpA,216) US(bC,hpA,224)
        UL(2,hpA,232)
        US(bD,hpA,240)  US(bA,hpA,248)
        gbuf[0][j] = acc0; gbuf[1][j] = acc1;
        BARRIER();

        // ---- layer 1 cell update (threads 0..511: unit u, batch bu) ----
        if (tid < 512) {
            float gi = sig_(gbuf[bu][u]);
            float gf = sig_(gbuf[bu][256 + u]);
            float gg = tanh_(gbuf[bu][512 + u]);
            float go = sig_(gbuf[bu][768 + u]);
            c1 = gf * c1 + gi * gg;
            hl1[p][bu][u] = (_Float16)(go * tanh_(c1));
        }
        BARRIER();

        // ---- layer 2 gates: b2 + Wih2*h1(t) [ch 32..63] + Whh2*h2(t-1) [64..95] ----
        // parked: ch 41 (L3 @B:k72), ch 53 (L4 @B:k168),
        //         ch 65 (L5 @C:k8), ch 77 (L6 @C:k104), ch 89 (L7 @C:k200)
        acc0 = bj2; acc1 = bj2;
        US(bB,hpB,0)    US(bC,hpB,8)   US(bD,hpB,16)  US(bA,hpB,24)
        US(bB,hpB,32)   US(bC,hpB,40)  US(bD,hpB,48)  US(bA,hpB,56)
        US(bB,hpB,64)
        UL(3,hpB,72)
        US(bC,hpB,80)   US(bD,hpB,88)  US(bA,hpB,96)  US(bB,hpB,104)
        US(bC,hpB,112)  US(bD,hpB,120) US(bA,hpB,128) US(bB,hpB,136)
        US(bC,hpB,144)  US(bD,hpB,152) US(bA,hpB,160)
        UL(4,hpB,168)
        US(bB,hpB,176)  US(bC,hpB,184) US(bD,hpB,192) US(bA,hpB,200)
        US(bB,hpB,208)  US(bC,hpB,216) US(bD,hpB,224) US(bA,hpB,232)
        US(bB,hpB,240)  US(bC,hpB,248)
        US(bD,hpC,0)
        UL(5,hpC,8)
        US(bA,hpC,16)   US(bB,hpC,24)  US(bC,hpC,32)  US(bD,hpC,40)
        US(bA,hpC,48)   US(bB,hpC,56)  US(bC,hpC,64)  US(bD,hpC,72)
        US(bA,hpC,80)   US(bB,hpC,88)  US(bC,hpC,96)
        UL(6,hpC,104)
        US(bD,hpC,112)  US(bA,hpC,120) US(bB,hpC,128) US(bC,hpC,136)
        US(bD,hpC,144)  US(bA,hpC,152) US(bB,hpC,160) US(bC,hpC,168)
        US(bD,hpC,176)  US(bA,hpC,184) US(bB,hpC,192)
        UL(7,hpC,200)
        US(bC,hpC,208)  US(bD,hpC,216) US(bA,hpC,224) US(bB,hpC,232)
        US(bC,hpC,240)  US(bD,hpC,248)
        gbuf[0][j] = acc0; gbuf[1][j] = acc1;
        BARRIER();

        // ---- layer 2 cell update ----
        if (tid < 512) {
            float gi = sig_(gbuf[bu][u]);
            float gf = sig_(gbuf[bu][256 + u]);
            float gg = tanh_(gbuf[bu][512 + u]);
            float go = sig_(gbuf[bu][768 + u]);
            c2 = gf * c2 + gi * gg;
            hl2[p][bu][u] = (_Float16)(go * tanh_(c2));
        }
        BARRIER();

        // ---- y = h2 @ W_lin.T + b_lin (waves 0..3) ----
        if (wv < 4) {
            vh4 hv = *(const vh4*)&hl2[p][ob][4 * lane];
            float s = (float)hv.x * wl0 + (float)hv.y * wl1
                    + (float)hv.z * wl2 + (float)hv.w * wl3;
            #pragma unroll
            for (int m = 32; m >= 1; m >>= 1) s += __shfl_xor(s, m, 64);
            if (lane == 0)
                out[(size_t)(b0 + ob) * 512 + t * 2 + oo] = s + blin;
        }

        // prefetch x for t+1 (wraps harmlessly at the end)
        const int tn = (t + 1) & (TSTEPS - 1);
        xv0 = *(const vf2*)(x + (size_t)(b0 + 0) * 512 + tn * 2);
        xv1 = *(const vf2*)(x + (size_t)(b0 + 1) * 512 + tn * 2);
    }
}

extern "C" void kernel_launch(void* const* d_in, const int* in_sizes, int n_in,
                              void* d_out, int out_size, void* d_ws, size_t ws_size,
                              hipStream_t stream) {
    const float* x     = (const float*)d_in[0];
    const float* W_ih1 = (const float*)d_in[1];
    const float* W_hh1 = (const float*)d_in[2];
    const float* b_ih1 = (const float*)d_in[3];
    const float* b_hh1 = (const float*)d_in[4];
    const float* W_ih2 = (const float*)d_in[5];
    const float* W_hh2 = (const float*)d_in[6];
    const float* b_ih2 = (const float*)d_in[7];
    const float* b_hh2 = (const float*)d_in[8];
    const float* W_lin = (const float*)d_in[9];
    const float* b_lin = (const float*)d_in[10];
    float* out = (float*)d_out;

    prep_kernel<<<256, 256, 0, stream>>>(W_ih1, W_hh1, b_ih1, b_hh1,
                                         W_ih2, W_hh2, b_ih2, b_hh2, d_ws);
    lstm_kernel<<<256, NT, 0, stream>>>(x, d_ws, W_lin, b_lin, out);
}

// Round 11
// 3395.814 us; speedup vs baseline: 4.3569x; 3.4269x over previous
//
#include <hip/hip_runtime.h>

// 2-layer LSTM (H=256, T=256, B=512, I=2) + linear head.
// 256 blocks x 1024 threads, 2 batches/block, t-loop in-kernel.
// Round-6 compact-loop structure (the ONLY register shape that doesn't
// spill on this toolchain: R7-R10's unrolled schedules / VGPR parks all
// spilled at the 64-VGPR allocator cap -> GB-scale scratch traffic).
// Changes vs R6:
//  (1) last 8 chunks (hh2 k=192..255) PARKED IN LDS (128 KB; identity
//      layout, rolled 8-iter consume loop, self-write/self-read per thread)
//      -> streamed 88/96 chunks/step.
//  (2) in-loop barriers are lgkmcnt-only inline asm (correctness proven
//      R9/R10): all global loads are thread-private and `out` is never
//      read back, so __syncthreads' vmcnt(0) drain of the weight prefetch
//      queue is unnecessary.
// h in LDS fp16 (same-address broadcast b128 reads, conflict-free), c in
// regs, 4 barriers/step, fdot2 via union sub-register views.
// Round-3 lesson: no cross-block exchange, ever.

typedef float vf2 __attribute__((ext_vector_type(2)));
typedef _Float16 vh2 __attribute__((ext_vector_type(2)));
typedef _Float16 vh4 __attribute__((ext_vector_type(4)));
typedef _Float16 vh8 __attribute__((ext_vector_type(8)));

#define NT 1024
#define TSTEPS 256
#define NCH 96            // logical chunks per step (chunk = 8 k x 1024 rows)
#define NSTRM 88          // streamed chunks per step (last 8 parked in LDS)
#define CHB 16384         // bytes per chunk = 1024 threads * 16 B
#define FS 393216         // fp32 table offset (floats) = 96*CHB/4

__global__ void prep_kernel(const float* __restrict__ W_ih1,
                            const float* __restrict__ W_hh1,
                            const float* __restrict__ b_ih1,
                            const float* __restrict__ b_hh1,
                            const float* __restrict__ W_ih2,
                            const float* __restrict__ W_hh2,
                            const float* __restrict__ b_ih2,
                            const float* __restrict__ b_hh2,
                            void* __restrict__ ws) {
    const int stride = gridDim.x * blockDim.x;
    const int idx = blockIdx.x * blockDim.x + threadIdx.x;
    _Float16* wh = (_Float16*)ws;
    float* wf = (float*)ws;
    // chunk ch (0..95) covers k = 8*ch..8*ch+7 for all 1024 gate-rows.
    // k<256: W_hh1 | k<512: W_ih2 | else W_hh2. Identity placement:
    // streamed = chunks 0..87, LDS-parked = chunks 88..95 (hh2 tail).
    for (int e = idx; e < NCH * 8192; e += stride) {
        int ch = e >> 13, rem = e & 8191, row = rem >> 3, i = rem & 7;
        int k = (ch << 3) + i;
        float v;
        if (k < 256)      v = W_hh1[row * 256 + k];
        else if (k < 512) v = W_ih2[row * 256 + (k - 256)];
        else              v = W_hh2[row * 256 + (k - 512)];
        wh[e] = (_Float16)v;
    }
    for (int j = idx; j < 1024; j += stride) {
        wf[FS + j]        = W_ih1[j * 2 + 0];
        wf[FS + 1024 + j] = W_ih1[j * 2 + 1];
        wf[FS + 2048 + j] = b_ih1[j] + b_hh1[j];
        wf[FS + 3072 + j] = b_ih2[j] + b_hh2[j];
    }
}

__device__ __forceinline__ float sig_(float v) {
    return 1.f / (1.f + __expf(-v));
}
__device__ __forceinline__ float tanh_(float v) {
    return 1.f - 2.f / (__expf(2.f * v) + 1.f);
}
__device__ __forceinline__ float fdot2_(vh2 a, vh2 b, float c) {
#if __has_builtin(__builtin_amdgcn_fdot2)
    return __builtin_amdgcn_fdot2(a, b, c, false);
#else
    return c + (float)a.x * (float)b.x + (float)a.y * (float)b.y;
#endif
}

union W8 { vh8 v; vh2 p[4]; };

// lgkm-only barrier: LDS drained, weight-stream vmem stays in flight.
#define BARRIER() __asm__ volatile("s_waitcnt lgkmcnt(0)\ns_barrier" ::: "memory")

__global__ __launch_bounds__(NT, 4) void lstm_kernel(
    const float* __restrict__ x,      // (512, 256, 2)
    const void* __restrict__ ws,
    const float* __restrict__ W_lin,  // (2, 256)
    const float* __restrict__ b_lin,  // (2,)
    float* __restrict__ out)          // (512, 256, 2)
{
    __shared__ float gbuf[2][1024];            // gate preacts [batch][row]
    __shared__ _Float16 hl1[2][2][256];        // h1 [parity][batch][unit]
    __shared__ _Float16 hl2[2][2][256];        // h2
    __shared__ char lds_park[8][CHB];          // 8 LDS-parked chunks (128 KB)

    const int tid = threadIdx.x;
    const int j = tid;                         // owned gate-row (gate*256+unit)
    const int u = tid & 255, bu = (tid >> 8) & 1;
    const int b0 = blockIdx.x * 2;
    const char* wstream = (const char*)ws;
    const float* wf = (const float*)ws;

    const float wx0 = wf[FS + j], wx1 = wf[FS + 1024 + j];
    const float bj1 = wf[FS + 2048 + j], bj2 = wf[FS + 3072 + j];

    // y-head: waves 0..3 -> (batch ob, output oo); lane covers 4 units
    const int lane = tid & 63, wv = tid >> 6;
    const int ob = (wv >> 1) & 1, oo = wv & 1;
    const float wl0 = W_lin[oo * 256 + 4 * lane + 0];
    const float wl1 = W_lin[oo * 256 + 4 * lane + 1];
    const float wl2 = W_lin[oo * 256 + 4 * lane + 2];
    const float wl3 = W_lin[oo * 256 + 4 * lane + 3];
    const float blin = b_lin[oo];

    for (int i = tid; i < 2 * 2 * 256; i += NT) {
        ((_Float16*)hl1)[i] = (_Float16)0.f;
        ((_Float16*)hl2)[i] = (_Float16)0.f;
    }

    float c1 = 0.f, c2 = 0.f;
    vf2 xv0 = *(const vf2*)(x + (size_t)(b0 + 0) * 512);
    vf2 xv1 = *(const vf2*)(x + (size_t)(b0 + 1) * 512);

    const int t16 = tid * 16;
    int sp = 0;                                // uniform stream byte offset
    float acc0, acc1;

    auto loadc = [&](vh8& dst) {
        dst = *(const vh8*)(wstream + sp + t16);
        sp += CHB;
        if (sp == NSTRM * CHB) sp = 0;
    };
    auto usec = [&](vh8 w, const _Float16 (*hp)[256], int k0) {
        W8 uw; uw.v = w;
        W8 ua; ua.v = *(const vh8*)&hp[0][k0];
        W8 ub; ub.v = *(const vh8*)&hp[1][k0];
        acc0 = fdot2_(uw.p[0], ua.p[0], acc0);
        acc0 = fdot2_(uw.p[1], ua.p[1], acc0);
        acc0 = fdot2_(uw.p[2], ua.p[2], acc0);
        acc0 = fdot2_(uw.p[3], ua.p[3], acc0);
        acc1 = fdot2_(uw.p[0], ub.p[0], acc1);
        acc1 = fdot2_(uw.p[1], ub.p[1], acc1);
        acc1 = fdot2_(uw.p[2], ub.p[2], acc1);
        acc1 = fdot2_(uw.p[3], ub.p[3], acc1);
    };

    // stage the 8 LDS-parked chunks (logical positions 88..95); each
    // thread later reads back only its own 16 B (self-write/self-read).
    for (int s = 0; s < 8; ++s)
        *(vh8*)&lds_park[s][t16] =
            *(const vh8*)(wstream + (size_t)(88 + s) * CHB + t16);

    vh8 bA, bB, bC, bD;
    loadc(bA); loadc(bB); loadc(bC); loadc(bD);
    __syncthreads();   // init barrier (full drain once is fine)

    auto gemm32 = [&](const _Float16 (*hp)[256]) {
        #pragma unroll 1
        for (int q = 0; q < 32; q += 4) {
            usec(bA, hp, 8 * q);      loadc(bA);
            usec(bB, hp, 8 * q + 8);  loadc(bB);
            usec(bC, hp, 8 * q + 16); loadc(bC);
            usec(bD, hp, 8 * q + 24); loadc(bD);
        }
    };
    auto gemm24 = [&](const _Float16 (*hp)[256]) {
        #pragma unroll 1
        for (int q = 0; q < 24; q += 4) {
            usec(bA, hp, 8 * q);      loadc(bA);
            usec(bB, hp, 8 * q + 8);  loadc(bB);
            usec(bC, hp, 8 * q + 16); loadc(bC);
            usec(bD, hp, 8 * q + 24); loadc(bD);
        }
    };

    #pragma unroll 1
    for (int t = 0; t < TSTEPS; ++t) {
        const int p = t & 1, pm = p ^ 1;

        // ---- layer 1 gates: b1 + Wih1*x_t + Whh1*h1(t-1) [ch 0..31] ----
        acc0 = bj1 + wx0 * xv0.x + wx1 * xv0.y;
        acc1 = bj1 + wx0 * xv1.x + wx1 * xv1.y;
        gemm32(hl1[pm]);
        gbuf[0][j] = acc0; gbuf[1][j] = acc1;
        BARRIER();

        // ---- layer 1 cell update (threads 0..511: unit u, batch bu) ----
        if (tid < 512) {
            float gi = sig_(gbuf[bu][u]);
            float gf = sig_(gbuf[bu][256 + u]);
            float gg = tanh_(gbuf[bu][512 + u]);
            float go = sig_(gbuf[bu][768 + u]);
            c1 = gf * c1 + gi * gg;
            hl1[p][bu][u] = (_Float16)(go * tanh_(c1));
        }
        BARRIER();

        // ---- layer 2 gates: b2 + Wih2*h1(t) [32..63] + Whh2*h2(t-1) [64..95] ----
        acc0 = bj2; acc1 = bj2;
        gemm32(hl1[p]);
        gemm24(hl2[pm]);                      // hh2 k = 0..191 (streamed)
        {                                     // hh2 k = 192..255 (LDS-parked)
            const _Float16 (*hp)[256] = hl2[pm];
            #pragma unroll 1
            for (int s = 0; s < 8; ++s) {
                vh8 t_ = *(const vh8*)&lds_park[s][t16];
                usec(t_, hp, 192 + 8 * s);
            }
        }
        gbuf[0][j] = acc0; gbuf[1][j] = acc1;
        BARRIER();

        // ---- layer 2 cell update ----
        if (tid < 512) {
            float gi = sig_(gbuf[bu][u]);
            float gf = sig_(gbuf[bu][256 + u]);
            float gg = tanh_(gbuf[bu][512 + u]);
            float go = sig_(gbuf[bu][768 + u]);
            c2 = gf * c2 + gi * gg;
            hl2[p][bu][u] = (_Float16)(go * tanh_(c2));
        }
        BARRIER();

        // ---- y = h2 @ W_lin.T + b_lin (waves 0..3) ----
        if (wv < 4) {
            vh4 hv = *(const vh4*)&hl2[p][ob][4 * lane];
            float s = (float)hv.x * wl0 + (float)hv.y * wl1
                    + (float)hv.z * wl2 + (float)hv.w * wl3;
            #pragma unroll
            for (int m = 32; m >= 1; m >>= 1) s += __shfl_xor(s, m, 64);
            if (lane == 0)
                out[(size_t)(b0 + ob) * 512 + t * 2 + oo] = s + blin;
        }

        // prefetch x for t+1 (wraps harmlessly at the end)
        const int tn = (t + 1) & (TSTEPS - 1);
        xv0 = *(const vf2*)(x + (size_t)(b0 + 0) * 512 + tn * 2);
        xv1 = *(const vf2*)(x + (size_t)(b0 + 1) * 512 + tn * 2);
    }
}

extern "C" void kernel_launch(void* const* d_in, const int* in_sizes, int n_in,
                              void* d_out, int out_size, void* d_ws, size_t ws_size,
                              hipStream_t stream) {
    const float* x     = (const float*)d_in[0];
    const float* W_ih1 = (const float*)d_in[1];
    const float* W_hh1 = (const float*)d_in[2];
    const float* b_ih1 = (const float*)d_in[3];
    const float* b_hh1 = (const float*)d_in[4];
    const float* W_ih2 = (const float*)d_in[5];
    const float* W_hh2 = (const float*)d_in[6];
    const float* b_ih2 = (const float*)d_in[7];
    const float* b_hh2 = (const float*)d_in[8];
    const float* W_lin = (const float*)d_in[9];
    const float* b_lin = (const float*)d_in[10];
    float* out = (float*)d_out;

    prep_kernel<<<256, 256, 0, stream>>>(W_ih1, W_hh1, b_ih1, b_hh1,
                                         W_ih2, W_hh2, b_ih2, b_hh2, d_ws);
    lstm_kernel<<<256, NT, 0, stream>>>(x, d_ws, W_lin, b_lin, out);
}

// Round 12
// 3280.580 us; speedup vs baseline: 4.5100x; 1.0351x over previous
//
#include <hip/hip_runtime.h>

// 2-layer LSTM (H=256, T=256, B=512, I=2) + linear head.
// 256 blocks x 512 threads, 2 batches/block, t-loop in-kernel.
// NEW vs R11: each thread owns TWO gate-rows (tid and tid+512) -> per
// chunk: 32 B weights + still only 2 LDS h-reads -> per-CU LDS h traffic
// halves (R11 analysis: 3072 b128/CU/step co-saturated the LDS pipe with
// the VMEM stream). 8 waves/CU (2/SIMD) is enough: the 4-buffer register
// pipeline covers L2 latency (proven R2).
// Kept from R11: 8 chunks LDS-parked (128 KB, identity layout, rolled
// loops only - R7-R10: unrolled schedules spill), lgkm-only barriers
// (weight prefetch stays in flight across s_barrier; proven R9-R11),
// h in LDS fp16 (same-address broadcast reads), c in regs, fdot2 via
// union sub-register views. Round-3 lesson: no cross-block exchange.

typedef float vf2 __attribute__((ext_vector_type(2)));
typedef _Float16 vh2 __attribute__((ext_vector_type(2)));
typedef _Float16 vh4 __attribute__((ext_vector_type(4)));
typedef _Float16 vh8 __attribute__((ext_vector_type(8)));

#define NT 512
#define TSTEPS 256
#define NCH 96            // logical chunks per step (chunk = 8 k x 1024 rows)
#define NSTRM 88          // streamed chunks per step (last 8 parked in LDS)
#define CHB 16384         // bytes per chunk = 512 threads * 32 B
#define FS 393216         // fp32 table offset (floats) = 96*CHB/4

__global__ void prep_kernel(const float* __restrict__ W_ih1,
                            const float* __restrict__ W_hh1,
                            const float* __restrict__ b_ih1,
                            const float* __restrict__ b_hh1,
                            const float* __restrict__ W_ih2,
                            const float* __restrict__ W_hh2,
                            const float* __restrict__ b_ih2,
                            const float* __restrict__ b_hh2,
                            void* __restrict__ ws) {
    const int stride = gridDim.x * blockDim.x;
    const int idx = blockIdx.x * blockDim.x + threadIdx.x;
    _Float16* wh = (_Float16*)ws;
    float* wf = (float*)ws;
    // chunk ch (0..95) covers k = 8*ch..8*ch+7 for all 1024 gate-rows.
    // In-chunk: thread th holds rows {th, th+512}: element
    // e = ch*8192 + th*16 + r*8 + i  ->  row = th + 512*r, k = 8*ch + i.
    // k<256: W_hh1 | k<512: W_ih2 | else W_hh2. Streamed = ch 0..87,
    // LDS-parked = ch 88..95 (hh2 tail k=192..255).
    for (int e = idx; e < NCH * 8192; e += stride) {
        int ch = e >> 13, rem = e & 8191;
        int th = rem >> 4, r = (rem >> 3) & 1, i = rem & 7;
        int row = th + (r << 9);
        int k = (ch << 3) + i;
        float v;
        if (k < 256)      v = W_hh1[row * 256 + k];
        else if (k < 512) v = W_ih2[row * 256 + (k - 256)];
        else              v = W_hh2[row * 256 + (k - 512)];
        wh[e] = (_Float16)v;
    }
    for (int j = idx; j < 1024; j += stride) {
        wf[FS + j]        = W_ih1[j * 2 + 0];
        wf[FS + 1024 + j] = W_ih1[j * 2 + 1];
        wf[FS + 2048 + j] = b_ih1[j] + b_hh1[j];
        wf[FS + 3072 + j] = b_ih2[j] + b_hh2[j];
    }
}

__device__ __forceinline__ float sig_(float v) {
    return 1.f / (1.f + __expf(-v));
}
__device__ __forceinline__ float tanh_(float v) {
    return 1.f - 2.f / (__expf(2.f * v) + 1.f);
}
__device__ __forceinline__ float fdot2_(vh2 a, vh2 b, float c) {
#if __has_builtin(__builtin_amdgcn_fdot2)
    return __builtin_amdgcn_fdot2(a, b, c, false);
#else
    return c + (float)a.x * (float)b.x + (float)a.y * (float)b.y;
#endif
}

union W8 { vh8 v; vh2 p[4]; };
struct WPair { vh8 r0, r1; };   // weights for rows tid and tid+512 (8 k each)

// lgkm-only barrier: LDS drained, weight-stream vmem stays in flight.
#define BARRIER() __asm__ volatile("s_waitcnt lgkmcnt(0)\ns_barrier" ::: "memory")

__global__ __launch_bounds__(NT, 2) void lstm_kernel(
    const float* __restrict__ x,      // (512, 256, 2)
    const void* __restrict__ ws,
    const float* __restrict__ W_lin,  // (2, 256)
    const float* __restrict__ b_lin,  // (2,)
    float* __restrict__ out)          // (512, 256, 2)
{
    __shared__ float gbuf[2][1024];            // gate preacts [batch][row]
    __shared__ _Float16 hl1[2][2][256];        // h1 [parity][batch][unit]
    __shared__ _Float16 hl2[2][2][256];        // h2
    __shared__ char lds_park[8][CHB];          // 8 LDS-parked chunks (128 KB)

    const int tid = threadIdx.x;
    const int j = tid;                         // first owned gate-row; second is j+512
    const int u = tid & 255, bu = tid >> 8;    // cell-update: unit u, batch bu
    const int b0 = blockIdx.x * 2;
    const char* wstream = (const char*)ws;
    const float* wf = (const float*)ws;

    const float wx0a = wf[FS + j],        wx1a = wf[FS + 1024 + j];
    const float wx0b = wf[FS + 512 + j],  wx1b = wf[FS + 1536 + j];
    const float bj1a = wf[FS + 2048 + j], bj1b = wf[FS + 2560 + j];
    const float bj2a = wf[FS + 3072 + j], bj2b = wf[FS + 3584 + j];

    // y-head: waves 0..3 -> (batch ob, output oo); lane covers 4 units
    const int lane = tid & 63, wv = tid >> 6;
    const int ob = (wv >> 1) & 1, oo = wv & 1;
    const float wl0 = W_lin[oo * 256 + 4 * lane + 0];
    const float wl1 = W_lin[oo * 256 + 4 * lane + 1];
    const float wl2 = W_lin[oo * 256 + 4 * lane + 2];
    const float wl3 = W_lin[oo * 256 + 4 * lane + 3];
    const float blin = b_lin[oo];

    for (int i = tid; i < 2 * 2 * 256; i += NT) {
        ((_Float16*)hl1)[i] = (_Float16)0.f;
        ((_Float16*)hl2)[i] = (_Float16)0.f;
    }

    float c1 = 0.f, c2 = 0.f;
    vf2 xv0 = *(const vf2*)(x + (size_t)(b0 + 0) * 512);
    vf2 xv1 = *(const vf2*)(x + (size_t)(b0 + 1) * 512);

    const int t32 = tid * 32;
    int sp = 0;                                // uniform stream byte offset
    float a00, a01, a10, a11;                  // [row0/1][batch0/1]

    auto loadc = [&](WPair& d) {
        d.r0 = *(const vh8*)(wstream + sp + t32);
        d.r1 = *(const vh8*)(wstream + sp + t32 + 16);
        sp += CHB;
        if (sp == NSTRM * CHB) sp = 0;
    };
    auto usec = [&](const WPair& w, const _Float16 (*hp)[256], int k0) {
        W8 u0; u0.v = w.r0;
        W8 u1; u1.v = w.r1;
        W8 ha; ha.v = *(const vh8*)&hp[0][k0];
        W8 hb; hb.v = *(const vh8*)&hp[1][k0];
        a00 = fdot2_(u0.p[0], ha.p[0], a00); a00 = fdot2_(u0.p[1], ha.p[1], a00);
        a00 = fdot2_(u0.p[2], ha.p[2], a00); a00 = fdot2_(u0.p[3], ha.p[3], a00);
        a01 = fdot2_(u0.p[0], hb.p[0], a01); a01 = fdot2_(u0.p[1], hb.p[1], a01);
        a01 = fdot2_(u0.p[2], hb.p[2], a01); a01 = fdot2_(u0.p[3], hb.p[3], a01);
        a10 = fdot2_(u1.p[0], ha.p[0], a10); a10 = fdot2_(u1.p[1], ha.p[1], a10);
        a10 = fdot2_(u1.p[2], ha.p[2], a10); a10 = fdot2_(u1.p[3], ha.p[3], a10);
        a11 = fdot2_(u1.p[0], hb.p[0], a11); a11 = fdot2_(u1.p[1], hb.p[1], a11);
        a11 = fdot2_(u1.p[2], hb.p[2], a11); a11 = fdot2_(u1.p[3], hb.p[3], a11);
    };

    // stage the 8 LDS-parked chunks (logical 88..95); each thread reads
    // back only its own 32 B later (self-write/self-read).
    for (int s = 0; s < 8; ++s) {
        const char* src = wstream + (size_t)(88 + s) * CHB + t32;
        *(vh8*)&lds_park[s][t32]      = *(const vh8*)src;
        *(vh8*)&lds_park[s][t32 + 16] = *(const vh8*)(src + 16);
    }

    WPair bA, bB, bC, bD;
    loadc(bA); loadc(bB); loadc(bC); loadc(bD);
    __syncthreads();   // init barrier (full drain once is fine)

    auto gemm32 = [&](const _Float16 (*hp)[256]) {
        #pragma unroll 1
        for (int q = 0; q < 32; q += 4) {
            usec(bA, hp, 8 * q);      loadc(bA);
            usec(bB, hp, 8 * q + 8);  loadc(bB);
            usec(bC, hp, 8 * q + 16); loadc(bC);
            usec(bD, hp, 8 * q + 24); loadc(bD);
        }
    };
    auto gemm24 = [&](const _Float16 (*hp)[256]) {
        #pragma unroll 1
        for (int q = 0; q < 24; q += 4) {
            usec(bA, hp, 8 * q);      loadc(bA);
            usec(bB, hp, 8 * q + 8);  loadc(bB);
            usec(bC, hp, 8 * q + 16); loadc(bC);
            usec(bD, hp, 8 * q + 24); loadc(bD);
        }
    };

    #pragma unroll 1
    for (int t = 0; t < TSTEPS; ++t) {
        const int p = t & 1, pm = p ^ 1;

        // ---- layer 1 gates: b1 + Wih1*x_t + Whh1*h1(t-1) [ch 0..31] ----
        a00 = bj1a + wx0a * xv0.x + wx1a * xv0.y;
        a01 = bj1a + wx0a * xv1.x + wx1a * xv1.y;
        a10 = bj1b + wx0b * xv0.x + wx1b * xv0.y;
        a11 = bj1b + wx0b * xv1.x + wx1b * xv1.y;
        gemm32(hl1[pm]);
        gbuf[0][j] = a00; gbuf[1][j] = a01;
        gbuf[0][512 + j] = a10; gbuf[1][512 + j] = a11;
        BARRIER();

        // ---- layer 1 cell update (thread -> unit u, batch bu) ----
        {
            float gi = sig_(gbuf[bu][u]);
            float gf = sig_(gbuf[bu][256 + u]);
            float gg = tanh_(gbuf[bu][512 + u]);
            float go = sig_(gbuf[bu][768 + u]);
            c1 = gf * c1 + gi * gg;
            hl1[p][bu][u] = (_Float16)(go * tanh_(c1));
        }
        BARRIER();

        // ---- layer 2 gates: b2 + Wih2*h1(t) [32..63] + Whh2*h2(t-1) [64..95] ----
        a00 = bj2a; a01 = bj2a; a10 = bj2b; a11 = bj2b;
        gemm32(hl1[p]);
        gemm24(hl2[pm]);                      // hh2 k = 0..191 (streamed)
        {                                     // hh2 k = 192..255 (LDS-parked)
            const _Float16 (*hp)[256] = hl2[pm];
            #pragma unroll 1
            for (int s = 0; s < 8; ++s) {
                WPair w;
                w.r0 = *(const vh8*)&lds_park[s][t32];
                w.r1 = *(const vh8*)&lds_park[s][t32 + 16];
                usec(w, hp, 192 + 8 * s);
            }
        }
        gbuf[0][j] = a00; gbuf[1][j] = a01;
        gbuf[0][512 + j] = a10; gbuf[1][512 + j] = a11;
        BARRIER();

        // ---- layer 2 cell update ----
        {
            float gi = sig_(gbuf[bu][u]);
            float gf = sig_(gbuf[bu][256 + u]);
            float gg = tanh_(gbuf[bu][512 + u]);
            float go = sig_(gbuf[bu][768 + u]);
            c2 = gf * c2 + gi * gg;
            hl2[p][bu][u] = (_Float16)(go * tanh_(c2));
        }
        BARRIER();

        // ---- y = h2 @ W_lin.T + b_lin (waves 0..3) ----
        if (wv < 4) {
            vh4 hv = *(const vh4*)&hl2[p][ob][4 * lane];
            float s = (float)hv.x * wl0 + (float)hv.y * wl1
                    + (float)hv.z * wl2 + (float)hv.w * wl3;
            #pragma unroll
            for (int m = 32; m >= 1; m >>= 1) s += __shfl_xor(s, m, 64);
            if (lane == 0)
                out[(size_t)(b0 + ob) * 512 + t * 2 + oo] = s + blin;
        }

        // prefetch x for t+1 (wraps harmlessly at the end)
        const int tn = (t + 1) & (TSTEPS - 1);
        xv0 = *(const vf2*)(x + (size_t)(b0 + 0) * 512 + tn * 2);
        xv1 = *(const vf2*)(x + (size_t)(b0 + 1) * 512 + tn * 2);
    }
}

extern "C" void kernel_launch(void* const* d_in, const int* in_sizes, int n_in,
                              void* d_out, int out_size, void* d_ws, size_t ws_size,
                              hipStream_t stream) {
    const float* x     = (const float*)d_in[0];
    const float* W_ih1 = (const float*)d_in[1];
    const float* W_hh1 = (const float*)d_in[2];
    const float* b_ih1 = (const float*)d_in[3];
    const float* b_hh1 = (const float*)d_in[4];
    const float* W_ih2 = (const float*)d_in[5];
    const float* W_hh2 = (const float*)d_in[6];
    const float* b_ih2 = (const float*)d_in[7];
    const float* b_hh2 = (const float*)d_in[8];
    const float* W_lin = (const float*)d_in[9];
    const float* b_lin = (const float*)d_in[10];
    float* out = (float*)d_out;

    prep_kernel<<<256, 256, 0, stream>>>(W_ih1, W_hh1, b_ih1, b_hh1,
                                         W_ih2, W_hh2, b_ih2, b_hh2, d_ws);
    lstm_kernel<<<256, NT, 0, stream>>>(x, d_ws, W_lin, b_lin, out);
}